// Round 12
// baseline (488.163 us; speedup 1.0000x reference)
//
#include <hip/hip_runtime.h>
#include <stdint.h>

#define HID 128
#define EDIM 32

typedef __attribute__((ext_vector_type(8))) short bf16x8;
typedef __attribute__((ext_vector_type(4))) float f4_t;

static __device__ __forceinline__ unsigned short f2bf(float f) {
  union { float f; unsigned int u; } v; v.f = f;
  return (unsigned short)((v.u + 0x7fffu + ((v.u >> 16) & 1u)) >> 16);
}

static __device__ __forceinline__ float bf2f(short s) {
  union { unsigned int u; float f; } v;
  v.u = ((unsigned int)(unsigned short)s) << 16;
  return v.f;
}

static __device__ __forceinline__ void atomAddF(float* p, float v) {
#if defined(__gfx950__) || defined(__gfx942__) || defined(__gfx90a__)
  unsafeAtomicAdd(p, v);
#else
  atomicAdd(p, v);
#endif
}

// ---------------------------------------------------------------------------
// Pass 1: histogram of dst + x_perm build:
//   x_perm[node][(c&15)*8 + (c>>4)] = bf16(x[node][c])
// ---------------------------------------------------------------------------
__global__ __launch_bounds__(256) void hist_xperm(const int* __restrict__ ei,
                                                  const float* __restrict__ x,
                                                  unsigned int* __restrict__ counts,
                                                  unsigned short* __restrict__ xPerm,
                                                  int nE, int nNodes, int doPerm) {
  int tid = blockIdx.x * blockDim.x + threadIdx.x;
  const int stride = gridDim.x * blockDim.x;
  for (int i = tid; i < nE; i += stride) atomicAdd(&counts[ei[nE + i]], 1u);
  if (doPerm) {
    const int nCh = nNodes * 16;
    for (int j = tid; j < nCh; j += stride) {
      const int node = j >> 4, g = j & 15;
      const float* xp = x + (size_t)node * HID + g;
      bf16x8 o;
#pragma unroll
      for (int k = 0; k < 8; ++k) o[k] = (short)f2bf(xp[k * 16]);
      *(bf16x8*)(xPerm + (size_t)node * HID + g * 8) = o;
    }
  }
}

// ---------------------------------------------------------------------------
// Chunked exclusive scan of counts[N] -> offsets[N+1]; also fills cursors.
// ---------------------------------------------------------------------------
__global__ __launch_bounds__(1024) void chunk_sum(const unsigned int* __restrict__ counts,
                                                  unsigned int* __restrict__ chunkSum, int N) {
  __shared__ unsigned int wsum[16];
  const int tid = threadIdx.x;
  const int i = blockIdx.x * 1024 + tid;
  unsigned int v = (i < N) ? counts[i] : 0u;
#pragma unroll
  for (int d = 1; d < 64; d <<= 1) v += (unsigned int)__shfl_xor((int)v, d);
  if ((tid & 63) == 0) wsum[tid >> 6] = v;
  __syncthreads();
  if (tid < 16) {
    unsigned int t = wsum[tid];
#pragma unroll
    for (int d = 1; d < 16; d <<= 1) t += (unsigned int)__shfl_xor((int)t, d);
    if (tid == 0) chunkSum[blockIdx.x] = t;
  }
}

__global__ __launch_bounds__(256) void scan_chunks(const unsigned int* __restrict__ chunkSum,
                                                   unsigned int* __restrict__ chunkOff,
                                                   unsigned int* __restrict__ offsets,
                                                   int nChunks, int N) {
  __shared__ unsigned int wsum[4];
  const int tid = threadIdx.x, lane = tid & 63, w = tid >> 6;
  unsigned int v = (tid < nChunks) ? chunkSum[tid] : 0u;
  unsigned int s = v;
#pragma unroll
  for (int d = 1; d < 64; d <<= 1) {
    unsigned int t = (unsigned int)__shfl_up((int)s, d);
    if (lane >= d) s += t;
  }
  if (lane == 63) wsum[w] = s;
  __syncthreads();
  unsigned int wOff = 0;
  for (int k = 0; k < w; ++k) wOff += wsum[k];
  if (tid < nChunks) chunkOff[tid] = wOff + s - v;
  if (tid == nChunks - 1) offsets[N] = wOff + s;
}

__global__ __launch_bounds__(1024) void scan_local(const unsigned int* __restrict__ counts,
                                                   const unsigned int* __restrict__ chunkOff,
                                                   unsigned int* __restrict__ offsets,
                                                   unsigned int* __restrict__ cursors, int N) {
  __shared__ unsigned int wsum[16];
  const int tid = threadIdx.x, lane = tid & 63, w = tid >> 6;
  const int i = blockIdx.x * 1024 + tid;
  unsigned int v = (i < N) ? counts[i] : 0u;
  unsigned int s = v;
#pragma unroll
  for (int d = 1; d < 64; d <<= 1) {
    unsigned int t = (unsigned int)__shfl_up((int)s, d);
    if (lane >= d) s += t;
  }
  if (lane == 63) wsum[w] = s;
  __syncthreads();
  unsigned int wOff = 0;
  for (int k = 0; k < w; ++k) wOff += wsum[k];
  if (i < N) {
    const unsigned int ex = chunkOff[blockIdx.x] + wOff + (s - v);
    offsets[i] = ex;
    cursors[i] = ex;
  }
}

// ---------------------------------------------------------------------------
// Fused scatter + ea convert: 4 lanes per edge. Writes sortedSrc[pos] (4 B)
// and eaSorted[pos] (64 B bf16 row, NORMAL stores so L3 keeps them for agg).
// ---------------------------------------------------------------------------
__global__ __launch_bounds__(256) void scatter_conv(const int* __restrict__ ei,
                                                    const float* __restrict__ ea,
                                                    unsigned int* __restrict__ cursors,
                                                    unsigned int* __restrict__ sortedSrc,
                                                    unsigned short* __restrict__ eaSorted,
                                                    int nE) {
  const int lane = threadIdx.x & 63;
  const int q = lane & 3;
  int t = blockIdx.x * blockDim.x + threadIdx.x;
  const int eStride = (gridDim.x * blockDim.x) >> 2;
  for (int e = t >> 2; e < nE; e += eStride) {
    unsigned int pos = 0;
    if (q == 0) {
      const int d = ei[nE + e];
      pos = atomicAdd(&cursors[d], 1u);
      sortedSrc[pos] = (unsigned int)ei[e];
    }
    pos = (unsigned int)__shfl((int)pos, lane & ~3);
    const f4_t* ap = (const f4_t*)(ea + (size_t)e * EDIM + q * 8);
    f4_t a0 = __builtin_nontemporal_load(ap);
    f4_t a1 = __builtin_nontemporal_load(ap + 1);
    bf16x8 o;
#pragma unroll
    for (int k = 0; k < 4; ++k) { o[k] = (short)f2bf(a0[k]); o[k + 4] = (short)f2bf(a1[k]); }
    *(bf16x8*)(eaSorted + (size_t)pos * EDIM + q * 8) = o;
  }
}

// Fallback scatter (minimal workspace): eid + src.
__global__ __launch_bounds__(256) void scatter_min(const int* __restrict__ ei,
                                                   unsigned int* __restrict__ cursors,
                                                   unsigned int* __restrict__ sortedEid,
                                                   unsigned int* __restrict__ sortedSrc,
                                                   int nE) {
  int i = blockIdx.x * blockDim.x + threadIdx.x;
  const int stride = gridDim.x * blockDim.x;
  for (; i < nE; i += stride) {
    const int d = ei[nE + i];
    const unsigned int pos = atomicAdd(&cursors[d], 1u);
    sortedEid[pos] = (unsigned int)i;
    sortedSrc[pos] = (unsigned int)ei[i];
  }
}

// ---------------------------------------------------------------------------
// Pair aggregation (r10 exact): one wave per TWO adjacent nodes, both load
// chains in flight together. Register accumulators + shfl reduce; no atomics.
// Natural VGPR (112) -> 4 waves/SIMD. 3-chain variants regressed twice
// (r7: shfl GETSRC; r11: sched_barrier pin) -- this is the local optimum.
// ---------------------------------------------------------------------------
template <int BF16H>
__global__ __launch_bounds__(256) void agg_pair(
    const float* __restrict__ x, const unsigned short* __restrict__ xPerm,
    const unsigned short* __restrict__ eaSorted, const unsigned int* __restrict__ sortedSrc,
    const float* __restrict__ W, const float* __restrict__ bias,
    const unsigned int* __restrict__ offsets, float* __restrict__ h,
    unsigned short* __restrict__ hBf, int nNodes, int nPairs) {
  const int lane = threadIdx.x & 63;
  const int l15 = lane & 15;
  const int lq  = lane >> 4;

  bf16x8 Wf[8];
  float bv[8];
#pragma unroll
  for (int nt = 0; nt < 8; ++nt) {
#pragma unroll
    for (int j = 0; j < 8; ++j)
      Wf[nt][j] = (short)f2bf(W[(8 * lq + j) * HID + 16 * nt + l15]);
    bv[nt] = bias[16 * nt + l15];
  }

  int waveId = blockIdx.x * 4 + ((int)threadIdx.x >> 6);
  const int nWaves = gridDim.x * 4;

  auto LOADT = [&](unsigned int b, unsigned int end, bf16x8& af, bf16x8* xg) {
    const unsigned int sA = b + (unsigned int)l15;
    if (sA < end)
      af = __builtin_nontemporal_load((const bf16x8*)(eaSorted + (size_t)sA * EDIM + lq * 8));
    else
      af = bf16x8{0, 0, 0, 0, 0, 0, 0, 0};
#pragma unroll
    for (int r = 0; r < 4; ++r) {
      unsigned int sl = b + (unsigned int)(lq * 4 + r);
      unsigned int cl = sl < end ? sl : end - 1;
      const unsigned int src = sortedSrc[cl];
      xg[r] = *(const bf16x8*)(xPerm + (size_t)src * HID + l15 * 8);
    }
  };

  for (int p = waveId; p < nPairs; p += nWaves) {
    const int nA = p * 2;
    const int nB = (nA + 1 < nNodes) ? nA + 1 : nA;
    unsigned int bA = offsets[nA];
    const unsigned int eA = offsets[nA + 1];
    unsigned int bB = offsets[nB];
    const unsigned int eB = offsets[nB + 1];

    float accA[8] = {0, 0, 0, 0, 0, 0, 0, 0};
    float accB[8] = {0, 0, 0, 0, 0, 0, 0, 0};

    while (bA < eA || bB < eB) {
      const bool mA = bA < eA, mB = bB < eB;
      bf16x8 afA, afB, xgA[4], xgB[4];
      if (mA) LOADT(bA, eA, afA, xgA);
      if (mB) LOADT(bB, eB, afB, xgB);

      if (mA) {
        f4_t acc[8];
#pragma unroll
        for (int nt = 0; nt < 8; ++nt) {
          f4_t c; c[0] = bv[nt]; c[1] = bv[nt]; c[2] = bv[nt]; c[3] = bv[nt];
          acc[nt] = __builtin_amdgcn_mfma_f32_16x16x32_bf16(afA, Wf[nt], c, 0, 0, 0);
        }
#pragma unroll
        for (int r = 0; r < 4; ++r) {
          if (bA + (unsigned int)(lq * 4 + r) < eA) {
#pragma unroll
            for (int nt = 0; nt < 8; ++nt)
              accA[nt] += fmaxf(acc[nt][r] + bf2f(xgA[r][nt]), 0.f);
          }
        }
        bA += 16;
      }

      if (mB) {
        f4_t acc[8];
#pragma unroll
        for (int nt = 0; nt < 8; ++nt) {
          f4_t c; c[0] = bv[nt]; c[1] = bv[nt]; c[2] = bv[nt]; c[3] = bv[nt];
          acc[nt] = __builtin_amdgcn_mfma_f32_16x16x32_bf16(afB, Wf[nt], c, 0, 0, 0);
        }
#pragma unroll
        for (int r = 0; r < 4; ++r) {
          if (bB + (unsigned int)(lq * 4 + r) < eB) {
#pragma unroll
            for (int nt = 0; nt < 8; ++nt)
              accB[nt] += fmaxf(acc[nt][r] + bf2f(xgB[r][nt]), 0.f);
          }
        }
        bB += 16;
      }
    }

#pragma unroll
    for (int nt = 0; nt < 8; ++nt) {
      accA[nt] += __shfl_xor(accA[nt], 16);
      accA[nt] += __shfl_xor(accA[nt], 32);
      accB[nt] += __shfl_xor(accB[nt], 16);
      accB[nt] += __shfl_xor(accB[nt], 32);
    }

    const int c0 = 32 * lq + l15;
    const size_t rowA = (size_t)nA * HID;
    const size_t rowB = (size_t)nB * HID;
    if (BF16H) {
      const unsigned int xvA = *(const unsigned int*)(xPerm + rowA + l15 * 8 + 2 * lq);
      const unsigned int xvB = *(const unsigned int*)(xPerm + rowB + l15 * 8 + 2 * lq);
      hBf[rowA + c0]      = f2bf(accA[2 * lq]     + bf2f((short)(xvA & 0xffffu)));
      hBf[rowA + c0 + 16] = f2bf(accA[2 * lq + 1] + bf2f((short)(xvA >> 16)));
      hBf[rowB + c0]      = f2bf(accB[2 * lq]     + bf2f((short)(xvB & 0xffffu)));
      hBf[rowB + c0 + 16] = f2bf(accB[2 * lq + 1] + bf2f((short)(xvB >> 16)));
    } else {
      h[rowA + c0]      = accA[2 * lq]     + x[rowA + c0];
      h[rowA + c0 + 16] = accA[2 * lq + 1] + x[rowA + c0 + 16];
      h[rowB + c0]      = accB[2 * lq]     + x[rowB + c0];
      h[rowB + c0 + 16] = accB[2 * lq + 1] + x[rowB + c0 + 16];
    }
  }
}

// ---------------------------------------------------------------------------
// Fallback aggregation (minimal workspace): per-node waves, f32 gathers.
// ---------------------------------------------------------------------------
__global__ __launch_bounds__(256) void agg_fb(
    const float* __restrict__ x, const float* __restrict__ ea,
    const float* __restrict__ W, const float* __restrict__ bias,
    const unsigned int* __restrict__ offsets, const unsigned int* __restrict__ sortedEid,
    const unsigned int* __restrict__ sortedSrc, float* __restrict__ h, int nNodes) {
  const int lane = threadIdx.x & 63;
  const int l15 = lane & 15;
  const int lq  = lane >> 4;

  bf16x8 Wf[8];
  float bv[8];
#pragma unroll
  for (int nt = 0; nt < 8; ++nt) {
#pragma unroll
    for (int j = 0; j < 8; ++j)
      Wf[nt][j] = (short)f2bf(W[(8 * lq + j) * HID + 16 * nt + l15]);
    bv[nt] = bias[16 * nt + l15];
  }

  int waveId = blockIdx.x * 4 + ((int)threadIdx.x >> 6);
  const int nWaves = gridDim.x * 4;

  for (int n = waveId; n < nNodes; n += nWaves) {
    const unsigned int beg = offsets[n];
    const unsigned int end = offsets[n + 1];
    float accv[8] = {0, 0, 0, 0, 0, 0, 0, 0};

    for (unsigned int base = beg; base < end; base += 16) {
      bf16x8 af = {0, 0, 0, 0, 0, 0, 0, 0};
      const unsigned int slotA = base + (unsigned int)l15;
      if (slotA < end) {
        const unsigned int eidA = sortedEid[slotA];
        const float* ap = ea + (size_t)eidA * EDIM + 8 * lq;
        f4_t a0 = *(const f4_t*)ap;
        f4_t a1 = *(const f4_t*)(ap + 4);
#pragma unroll
        for (int j = 0; j < 4; ++j) { af[j] = (short)f2bf(a0[j]); af[j + 4] = (short)f2bf(a1[j]); }
      }
      f4_t acc[8];
#pragma unroll
      for (int nt = 0; nt < 8; ++nt) {
        f4_t c; c[0] = bv[nt]; c[1] = bv[nt]; c[2] = bv[nt]; c[3] = bv[nt];
        acc[nt] = __builtin_amdgcn_mfma_f32_16x16x32_bf16(af, Wf[nt], c, 0, 0, 0);
      }
#pragma unroll
      for (int r = 0; r < 4; ++r) {
        const unsigned int slot = base + (unsigned int)(lq * 4 + r);
        if (slot < end) {
          const int s = (int)sortedSrc[slot];
          const float* xp = x + (size_t)s * HID + l15;
#pragma unroll
          for (int nt = 0; nt < 8; ++nt)
            accv[nt] += fmaxf(acc[nt][r] + xp[nt * 16], 0.f);
        }
      }
    }

#pragma unroll
    for (int nt = 0; nt < 8; ++nt) {
      accv[nt] += __shfl_xor(accv[nt], 16);
      accv[nt] += __shfl_xor(accv[nt], 32);
    }
    const int c0 = 32 * lq + l15;
    const size_t rowOff = (size_t)n * HID;
    h[rowOff + c0]      = accv[2 * lq]     + x[rowOff + c0];
    h[rowOff + c0 + 16] = accv[2 * lq + 1] + x[rowOff + c0 + 16];
  }
}

// ---------------------------------------------------------------------------
// Node pass SPLIT (mode 2): two kernels, 32 KB LDS each -> 4-5 blocks/CU
// (vs fused 80 KB -> 2 blocks/CU, latency-bound at 2 waves/SIMD).
// node1: h1 = relu(hBf @ W1 + b1) -> h1Bf   (C-layout scalar bf16 stores)
// node2: h2 = h1Bf @ W2 + b2 -> hBf in place, + stats
// ---------------------------------------------------------------------------
__global__ __launch_bounds__(256) void node1_bf(
    const unsigned short* __restrict__ hBf, const float* __restrict__ W1,
    const float* __restrict__ b1, unsigned short* __restrict__ h1Bf,
    int nNodes, int nTiles) {
  __shared__ unsigned short sW1[128 * 128];
  for (int idx = threadIdx.x; idx < 128 * 128; idx += 256) {
    int n = idx & 127, k = idx >> 7;
    int off = n * 128 + ((((k >> 3) ^ (n & 15))) << 3) + (k & 7);
    sW1[off] = f2bf(W1[k * HID + n]);
  }
  __syncthreads();

  const int lane = threadIdx.x & 63;
  const int l15 = lane & 15, lq = lane >> 4;
  float b1v[8];
#pragma unroll
  for (int nt = 0; nt < 8; ++nt) b1v[nt] = b1[nt * 16 + l15];

  int waveId = blockIdx.x * 4 + ((int)threadIdx.x >> 6);
  const int nWaves = gridDim.x * 4;

  for (int tile = waveId; tile < nTiles; tile += nWaves) {
    const int r0 = tile << 4;
    int rr = r0 + l15; if (rr >= nNodes) rr = nNodes - 1;

    bf16x8 af[4];
    const unsigned short* hp = hBf + (size_t)rr * HID;
#pragma unroll
    for (int kt = 0; kt < 4; ++kt)
      af[kt] = *(const bf16x8*)(hp + kt * 32 + 8 * lq);

    f4_t acc[8];
#pragma unroll
    for (int nt = 0; nt < 8; ++nt) {
      f4_t c; c[0] = b1v[nt]; c[1] = b1v[nt]; c[2] = b1v[nt]; c[3] = b1v[nt];
#pragma unroll
      for (int kt = 0; kt < 4; ++kt) {
        bf16x8 wf = *(const bf16x8*)&sW1[(nt * 16 + l15) * 128 + ((((kt * 4 + lq) ^ l15)) << 3)];
        c = __builtin_amdgcn_mfma_f32_16x16x32_bf16(af[kt], wf, c, 0, 0, 0);
      }
      acc[nt] = c;
    }

    // write h1 in C-layout: row = r0 + lq*4 + r, col = nt*16 + l15
#pragma unroll
    for (int nt = 0; nt < 8; ++nt) {
#pragma unroll
      for (int r = 0; r < 4; ++r) {
        const int row = r0 + lq * 4 + r;
        if (row < nNodes)
          h1Bf[(size_t)row * HID + nt * 16 + l15] = f2bf(fmaxf(acc[nt][r], 0.f));
      }
    }
  }
}

__global__ __launch_bounds__(256) void node2_bf(
    const unsigned short* __restrict__ h1Bf, const float* __restrict__ W2,
    const float* __restrict__ b2, unsigned short* __restrict__ hBf,
    float* __restrict__ stats, int nNodes, int nTiles) {
  __shared__ unsigned short sW2[128 * 128];
  for (int idx = threadIdx.x; idx < 128 * 128; idx += 256) {
    int n = idx & 127, k = idx >> 7;
    int off = n * 128 + ((((k >> 3) ^ (n & 15))) << 3) + (k & 7);
    sW2[off] = f2bf(W2[k * HID + n]);
  }
  __syncthreads();

  const int lane = threadIdx.x & 63;
  const int l15 = lane & 15, lq = lane >> 4;
  float b2v[8];
#pragma unroll
  for (int nt = 0; nt < 8; ++nt) b2v[nt] = b2[nt * 16 + l15];
  float ssum[8] = {0, 0, 0, 0, 0, 0, 0, 0};
  float ssq[8]  = {0, 0, 0, 0, 0, 0, 0, 0};

  int waveId = blockIdx.x * 4 + ((int)threadIdx.x >> 6);
  const int nWaves = gridDim.x * 4;

  for (int tile = waveId; tile < nTiles; tile += nWaves) {
    const int r0 = tile << 4;
    int rr = r0 + l15; if (rr >= nNodes) rr = nNodes - 1;

    bf16x8 af[4];
    const unsigned short* hp = h1Bf + (size_t)rr * HID;
#pragma unroll
    for (int kt = 0; kt < 4; ++kt)
      af[kt] = *(const bf16x8*)(hp + kt * 32 + 8 * lq);

    f4_t acc[8];
#pragma unroll
    for (int nt = 0; nt < 8; ++nt) {
      f4_t c; c[0] = b2v[nt]; c[1] = b2v[nt]; c[2] = b2v[nt]; c[3] = b2v[nt];
#pragma unroll
      for (int kt = 0; kt < 4; ++kt) {
        bf16x8 wf = *(const bf16x8*)&sW2[(nt * 16 + l15) * 128 + ((((kt * 4 + lq) ^ l15)) << 3)];
        c = __builtin_amdgcn_mfma_f32_16x16x32_bf16(af[kt], wf, c, 0, 0, 0);
      }
      acc[nt] = c;
    }

#pragma unroll
    for (int nt = 0; nt < 8; ++nt) {
#pragma unroll
      for (int r = 0; r < 4; ++r) {
        const int row = r0 + lq * 4 + r;
        if (row < nNodes) {
          float v = acc[nt][r];
          hBf[(size_t)row * HID + nt * 16 + l15] = f2bf(v);
          ssum[nt] += v; ssq[nt] += v * v;
        }
      }
    }
  }

#pragma unroll
  for (int nt = 0; nt < 8; ++nt) {
    float a = ssum[nt], b = ssq[nt];
    a += __shfl_xor(a, 16); b += __shfl_xor(b, 16);
    a += __shfl_xor(a, 32); b += __shfl_xor(b, 32);
    if (lq == 0) {
      atomAddF(&stats[nt * 16 + l15], a);
      atomAddF(&stats[HID + nt * 16 + l15], b);
    }
  }
}

// ---------------------------------------------------------------------------
// Fused node pass (fallback, f32 h): h1 = relu(h@W1+b1) ; h2 = h1@W2+b2
// ---------------------------------------------------------------------------
__global__ __launch_bounds__(256) void node_kernel(
    float* __restrict__ hF, const float* __restrict__ W1, const float* __restrict__ b1,
    const float* __restrict__ W2, const float* __restrict__ b2,
    float* __restrict__ stats, int nNodes, int nTiles) {
  __shared__ unsigned short sW1[128 * 128];
  __shared__ unsigned short sW2[128 * 128];
  __shared__ unsigned short sH1[4][16 * 128];

  for (int idx = threadIdx.x; idx < 128 * 128; idx += 256) {
    int n = idx & 127, k = idx >> 7;
    int off = n * 128 + ((((k >> 3) ^ (n & 15))) << 3) + (k & 7);
    sW1[off] = f2bf(W1[k * HID + n]);
    sW2[off] = f2bf(W2[k * HID + n]);
  }
  __syncthreads();

  const int lane = threadIdx.x & 63;
  const int l15 = lane & 15, lq = lane >> 4;
  const int wv = threadIdx.x >> 6;
  unsigned short* hb = &sH1[wv][0];

  float b1v[8], b2v[8];
#pragma unroll
  for (int nt = 0; nt < 8; ++nt) { b1v[nt] = b1[nt * 16 + l15]; b2v[nt] = b2[nt * 16 + l15]; }
  float ssum[8] = {0, 0, 0, 0, 0, 0, 0, 0};
  float ssq[8]  = {0, 0, 0, 0, 0, 0, 0, 0};

  int waveId = blockIdx.x * 4 + wv;
  const int nWaves = gridDim.x * 4;

  for (int tile = waveId; tile < nTiles; tile += nWaves) {
    const int r0 = tile << 4;
    int rr = r0 + l15; if (rr >= nNodes) rr = nNodes - 1;

    bf16x8 af[4];
    const float* hp = hF + (size_t)rr * HID;
#pragma unroll
    for (int kt = 0; kt < 4; ++kt) {
      const int k0 = kt * 32 + 8 * lq;
      f4_t u0 = *(const f4_t*)(hp + k0);
      f4_t u1 = *(const f4_t*)(hp + k0 + 4);
#pragma unroll
      for (int j = 0; j < 4; ++j) {
        af[kt][j]     = (short)f2bf(u0[j]);
        af[kt][j + 4] = (short)f2bf(u1[j]);
      }
    }

    f4_t acc[8];
#pragma unroll
    for (int nt = 0; nt < 8; ++nt) {
      f4_t c; c[0] = b1v[nt]; c[1] = b1v[nt]; c[2] = b1v[nt]; c[3] = b1v[nt];
#pragma unroll
      for (int kt = 0; kt < 4; ++kt) {
        bf16x8 wf = *(const bf16x8*)&sW1[(nt * 16 + l15) * 128 + ((((kt * 4 + lq) ^ l15)) << 3)];
        c = __builtin_amdgcn_mfma_f32_16x16x32_bf16(af[kt], wf, c, 0, 0, 0);
      }
      acc[nt] = c;
    }

#pragma unroll
    for (int nt = 0; nt < 8; ++nt) {
      const int ghi = 2 * nt + (l15 >> 3);
#pragma unroll
      for (int r = 0; r < 4; ++r) {
        const int row = lq * 4 + r;
        hb[row * 128 + ((ghi ^ (row & 15)) << 3) + (l15 & 7)] = f2bf(fmaxf(acc[nt][r], 0.f));
      }
    }
    asm volatile("s_waitcnt lgkmcnt(0)" ::: "memory");
    __builtin_amdgcn_sched_barrier(0);

    bf16x8 af2[4];
#pragma unroll
    for (int kt = 0; kt < 4; ++kt)
      af2[kt] = *(const bf16x8*)&hb[l15 * 128 + ((((kt * 4 + lq) ^ l15)) << 3)];

    f4_t acc2[8];
#pragma unroll
    for (int nt = 0; nt < 8; ++nt) {
      f4_t c; c[0] = b2v[nt]; c[1] = b2v[nt]; c[2] = b2v[nt]; c[3] = b2v[nt];
#pragma unroll
      for (int kt = 0; kt < 4; ++kt) {
        bf16x8 wf = *(const bf16x8*)&sW2[(nt * 16 + l15) * 128 + ((((kt * 4 + lq) ^ l15)) << 3)];
        c = __builtin_amdgcn_mfma_f32_16x16x32_bf16(af2[kt], wf, c, 0, 0, 0);
      }
      acc2[nt] = c;
    }

#pragma unroll
    for (int nt = 0; nt < 8; ++nt) {
#pragma unroll
      for (int r = 0; r < 4; ++r) {
        const int row = r0 + lq * 4 + r;
        if (row < nNodes) {
          float v = acc2[nt][r];
          hF[(size_t)row * HID + nt * 16 + l15] = v;
          ssum[nt] += v; ssq[nt] += v * v;
        }
      }
    }
  }

#pragma unroll
  for (int nt = 0; nt < 8; ++nt) {
    float a = ssum[nt], b = ssq[nt];
    a += __shfl_xor(a, 16); b += __shfl_xor(b, 16);
    a += __shfl_xor(a, 32); b += __shfl_xor(b, 32);
    if (lq == 0) {
      atomAddF(&stats[nt * 16 + l15], a);
      atomAddF(&stats[HID + nt * 16 + l15], b);
    }
  }
}

__global__ void norm_prep(float* __restrict__ stats, const float* __restrict__ gw,
                          const float* __restrict__ gb, const float* __restrict__ gs,
                          int nNodes) {
  int c = threadIdx.x;
  if (c < HID) {
    float invN = 1.f / (float)nNodes;
    float m   = stats[c] * invN;
    float msq = stats[HID + c] * invN;
    float s   = gs[c];
    float var = msq - (2.f * s - s * s) * m * m;
    float A = gw[c] * rsqrtf(var + 1e-5f);
    float B = gb[c] - A * s * m;
    stats[2 * HID + c] = A;
    stats[3 * HID + c] = B;
  }
}

// norm from bf16 h2 -> f32 out
__global__ __launch_bounds__(256) void norm_bf(const float* __restrict__ stats,
                                               const unsigned short* __restrict__ hBf,
                                               float* __restrict__ out, int total8) {
  const float* A = stats + 2 * HID;
  const float* B = stats + 3 * HID;
  int i = blockIdx.x * blockDim.x + threadIdx.x;
  const int stride = gridDim.x * blockDim.x;
  for (; i < total8; i += stride) {
    const int cg = (i & 15) * 8;
    bf16x8 hv = *(const bf16x8*)(hBf + (size_t)i * 8);
    f4_t a0 = *(const f4_t*)(A + cg), a1 = *(const f4_t*)(A + cg + 4);
    f4_t b0 = *(const f4_t*)(B + cg), b1 = *(const f4_t*)(B + cg + 4);
    f4_t o0, o1;
#pragma unroll
    for (int j = 0; j < 4; ++j) {
      o0[j] = fmaxf(fmaf(bf2f(hv[j]), a0[j], b0[j]), 0.f);
      o1[j] = fmaxf(fmaf(bf2f(hv[j + 4]), a1[j], b1[j]), 0.f);
    }
    f4_t* op = (f4_t*)(out + (size_t)i * 8);
    op[0] = o0; op[1] = o1;
  }
}

// in-place f32 norm (fallback)
__global__ __launch_bounds__(256) void norm_kernel(const float* __restrict__ stats,
                                                   float* __restrict__ out, int total4) {
  const f4_t* A4 = (const f4_t*)(stats + 2 * HID);
  const f4_t* B4 = (const f4_t*)(stats + 3 * HID);
  int i = blockIdx.x * blockDim.x + threadIdx.x;
  const int stride = gridDim.x * blockDim.x;
  for (; i < total4; i += stride) {
    const int cg = i & 31;
    f4_t h = ((const f4_t*)out)[i];
    f4_t a = A4[cg], b = B4[cg];
    f4_t o;
#pragma unroll
    for (int j = 0; j < 4; ++j) o[j] = fmaxf(fmaf(h[j], a[j], b[j]), 0.f);
    ((f4_t*)out)[i] = o;
  }
}

extern "C" void kernel_launch(void* const* d_in, const int* in_sizes, int n_in,
                              void* d_out, int out_size, void* d_ws, size_t ws_size,
                              hipStream_t stream) {
  const float* x  = (const float*)d_in[0];
  const int*   ei = (const int*)d_in[1];
  const float* ea = (const float*)d_in[2];
  const float* eW = (const float*)d_in[3];
  const float* eb = (const float*)d_in[4];
  const float* W1 = (const float*)d_in[5];
  const float* b1 = (const float*)d_in[6];
  const float* W2 = (const float*)d_in[7];
  const float* b2 = (const float*)d_in[8];
  const float* gw = (const float*)d_in[9];
  const float* gb = (const float*)d_in[10];
  const float* gs = (const float*)d_in[11];
  float* out = (float*)d_out;

  const int nNodes = in_sizes[0] / HID;   // 100000
  const int nE     = in_sizes[1] / 2;     // 1600000

  // ws layout
  char* w = (char*)d_ws;
  const size_t offStats   = 0;                                   // 4*HID f32
  const size_t offCounts  = 2048;
  const size_t offCursors = offCounts  + (size_t)nNodes * 4;
  const size_t offOffsets = offCursors + (size_t)nNodes * 4;
  const size_t offChunk   = offOffsets + (((size_t)(nNodes + 1) * 4 + 63) & ~63ull);
  const size_t offSS      = (offChunk + 2048 + 63) & ~63ull;     // nE u32
  const size_t offEaS     = offSS + (size_t)nE * 4;              // nE*EDIM bf16
  const size_t offXP      = offEaS + (size_t)nE * EDIM * 2;      // nNodes*HID bf16
  const size_t needFlat   = offXP + (size_t)nNodes * HID * 2;
  const size_t offHBf     = needFlat;                            // nNodes*HID bf16
  const size_t needBf     = offHBf + (size_t)nNodes * HID * 2;

  float* stats            = (float*)(w + offStats);
  unsigned int* counts    = (unsigned int*)(w + offCounts);
  unsigned int* cursors   = (unsigned int*)(w + offCursors);
  unsigned int* offsets   = (unsigned int*)(w + offOffsets);
  unsigned int* chunkSum  = (unsigned int*)(w + offChunk);
  unsigned int* chunkOff  = (unsigned int*)(w + offChunk + 1024);
  unsigned int* sortedSrc = (unsigned int*)(w + offSS);
  unsigned int* sortedEid = (unsigned int*)(w + offEaS);         // fb reuse
  unsigned short* eaSorted= (unsigned short*)(w + offEaS);
  unsigned short* xPerm   = (unsigned short*)(w + offXP);
  unsigned short* hBf     = (unsigned short*)(w + offHBf);
  unsigned short* h1Bf    = (unsigned short*)(w + offEaS);       // reuse after agg

  const int mode = (ws_size >= needBf) ? 2 : (ws_size >= needFlat ? 1 : 0);

  hipMemsetAsync(d_ws, 0, offCursors, stream);  // stats + counts

  hist_xperm<<<2048, 256, 0, stream>>>(ei, x, counts, xPerm, nE, nNodes, mode >= 1);

  const int nChunks = (nNodes + 1023) / 1024;
  chunk_sum<<<nChunks, 1024, 0, stream>>>(counts, chunkSum, nNodes);
  scan_chunks<<<1, 256, 0, stream>>>(chunkSum, chunkOff, offsets, nChunks, nNodes);
  scan_local<<<nChunks, 1024, 0, stream>>>(counts, chunkOff, offsets, cursors, nNodes);

  const int nTiles = (nNodes + 15) >> 4;

  if (mode >= 1) {
    scatter_conv<<<4096, 256, 0, stream>>>(ei, ea, cursors, sortedSrc, eaSorted, nE);
    const int nPairs = (nNodes + 1) / 2;
    const int blocks = (nPairs + 7) / 8;   // 2 pairs per wave
    if (mode == 2) {
      agg_pair<1><<<blocks, 256, 0, stream>>>(x, xPerm, eaSorted, sortedSrc, eW, eb,
                                              offsets, out, hBf, nNodes, nPairs);
      node1_bf<<<1024, 256, 0, stream>>>(hBf, W1, b1, h1Bf, nNodes, nTiles);
      node2_bf<<<1024, 256, 0, stream>>>(h1Bf, W2, b2, hBf, stats, nNodes, nTiles);
      norm_prep<<<1, 128, 0, stream>>>(stats, gw, gb, gs, nNodes);
      norm_bf<<<2048, 256, 0, stream>>>(stats, hBf, out, nNodes * (HID / 8));
    } else {
      agg_pair<0><<<blocks, 256, 0, stream>>>(x, xPerm, eaSorted, sortedSrc, eW, eb,
                                              offsets, out, hBf, nNodes, nPairs);
      node_kernel<<<512, 256, 0, stream>>>(out, W1, b1, W2, b2, stats, nNodes, nTiles);
      norm_prep<<<1, 128, 0, stream>>>(stats, gw, gb, gs, nNodes);
      norm_kernel<<<2048, 256, 0, stream>>>(stats, out, nNodes * (HID / 4));
    }
  } else {
    scatter_min<<<1024, 256, 0, stream>>>(ei, cursors, sortedEid, sortedSrc, nE);
    agg_fb<<<8192, 256, 0, stream>>>(x, ea, eW, eb, offsets, sortedEid, sortedSrc, out, nNodes);
    node_kernel<<<512, 256, 0, stream>>>(out, W1, b1, W2, b2, stats, nNodes, nTiles);
    norm_prep<<<1, 128, 0, stream>>>(stats, gw, gb, gs, nNodes);
    norm_kernel<<<2048, 256, 0, stream>>>(stats, out, nNodes * (HID / 4));
  }
}

// Round 13
// 483.539 us; speedup vs baseline: 1.0096x; 1.0096x over previous
//
#include <hip/hip_runtime.h>
#include <stdint.h>

#define HID 128
#define EDIM 32

typedef __attribute__((ext_vector_type(8))) short bf16x8;
typedef __attribute__((ext_vector_type(4))) float f4_t;

static __device__ __forceinline__ unsigned short f2bf(float f) {
  union { float f; unsigned int u; } v; v.f = f;
  return (unsigned short)((v.u + 0x7fffu + ((v.u >> 16) & 1u)) >> 16);
}

static __device__ __forceinline__ float bf2f(short s) {
  union { unsigned int u; float f; } v;
  v.u = ((unsigned int)(unsigned short)s) << 16;
  return v.f;
}

static __device__ __forceinline__ void atomAddF(float* p, float v) {
#if defined(__gfx950__) || defined(__gfx942__) || defined(__gfx90a__)
  unsafeAtomicAdd(p, v);
#else
  atomicAdd(p, v);
#endif
}

// ---------------------------------------------------------------------------
// Pass 1: histogram of dst + x_perm build:
//   x_perm[node][(c&15)*8 + (c>>4)] = bf16(x[node][c])
// ---------------------------------------------------------------------------
__global__ __launch_bounds__(256) void hist_xperm(const int* __restrict__ ei,
                                                  const float* __restrict__ x,
                                                  unsigned int* __restrict__ counts,
                                                  unsigned short* __restrict__ xPerm,
                                                  int nE, int nNodes, int doPerm) {
  int tid = blockIdx.x * blockDim.x + threadIdx.x;
  const int stride = gridDim.x * blockDim.x;
  for (int i = tid; i < nE; i += stride) atomicAdd(&counts[ei[nE + i]], 1u);
  if (doPerm) {
    const int nCh = nNodes * 16;
    for (int j = tid; j < nCh; j += stride) {
      const int node = j >> 4, g = j & 15;
      const float* xp = x + (size_t)node * HID + g;
      bf16x8 o;
#pragma unroll
      for (int k = 0; k < 8; ++k) o[k] = (short)f2bf(xp[k * 16]);
      *(bf16x8*)(xPerm + (size_t)node * HID + g * 8) = o;
    }
  }
}

// ---------------------------------------------------------------------------
// Chunked exclusive scan of counts[N] -> offsets[N+1]; also fills cursors.
// ---------------------------------------------------------------------------
__global__ __launch_bounds__(1024) void chunk_sum(const unsigned int* __restrict__ counts,
                                                  unsigned int* __restrict__ chunkSum, int N) {
  __shared__ unsigned int wsum[16];
  const int tid = threadIdx.x;
  const int i = blockIdx.x * 1024 + tid;
  unsigned int v = (i < N) ? counts[i] : 0u;
#pragma unroll
  for (int d = 1; d < 64; d <<= 1) v += (unsigned int)__shfl_xor((int)v, d);
  if ((tid & 63) == 0) wsum[tid >> 6] = v;
  __syncthreads();
  if (tid < 16) {
    unsigned int t = wsum[tid];
#pragma unroll
    for (int d = 1; d < 16; d <<= 1) t += (unsigned int)__shfl_xor((int)t, d);
    if (tid == 0) chunkSum[blockIdx.x] = t;
  }
}

__global__ __launch_bounds__(256) void scan_chunks(const unsigned int* __restrict__ chunkSum,
                                                   unsigned int* __restrict__ chunkOff,
                                                   unsigned int* __restrict__ offsets,
                                                   int nChunks, int N) {
  __shared__ unsigned int wsum[4];
  const int tid = threadIdx.x, lane = tid & 63, w = tid >> 6;
  unsigned int v = (tid < nChunks) ? chunkSum[tid] : 0u;
  unsigned int s = v;
#pragma unroll
  for (int d = 1; d < 64; d <<= 1) {
    unsigned int t = (unsigned int)__shfl_up((int)s, d);
    if (lane >= d) s += t;
  }
  if (lane == 63) wsum[w] = s;
  __syncthreads();
  unsigned int wOff = 0;
  for (int k = 0; k < w; ++k) wOff += wsum[k];
  if (tid < nChunks) chunkOff[tid] = wOff + s - v;
  if (tid == nChunks - 1) offsets[N] = wOff + s;
}

__global__ __launch_bounds__(1024) void scan_local(const unsigned int* __restrict__ counts,
                                                   const unsigned int* __restrict__ chunkOff,
                                                   unsigned int* __restrict__ offsets,
                                                   unsigned int* __restrict__ cursors, int N) {
  __shared__ unsigned int wsum[16];
  const int tid = threadIdx.x, lane = tid & 63, w = tid >> 6;
  const int i = blockIdx.x * 1024 + tid;
  unsigned int v = (i < N) ? counts[i] : 0u;
  unsigned int s = v;
#pragma unroll
  for (int d = 1; d < 64; d <<= 1) {
    unsigned int t = (unsigned int)__shfl_up((int)s, d);
    if (lane >= d) s += t;
  }
  if (lane == 63) wsum[w] = s;
  __syncthreads();
  unsigned int wOff = 0;
  for (int k = 0; k < w; ++k) wOff += wsum[k];
  if (i < N) {
    const unsigned int ex = chunkOff[blockIdx.x] + wOff + (s - v);
    offsets[i] = ex;
    cursors[i] = ex;
  }
}

// ---------------------------------------------------------------------------
// Fused scatter + ea convert: 4 lanes per edge. Writes sortedSrc[pos] (4 B)
// and eaSorted[pos] (64 B bf16 row, NORMAL stores so L3 keeps them for agg).
// ---------------------------------------------------------------------------
__global__ __launch_bounds__(256) void scatter_conv(const int* __restrict__ ei,
                                                    const float* __restrict__ ea,
                                                    unsigned int* __restrict__ cursors,
                                                    unsigned int* __restrict__ sortedSrc,
                                                    unsigned short* __restrict__ eaSorted,
                                                    int nE) {
  const int lane = threadIdx.x & 63;
  const int q = lane & 3;
  int t = blockIdx.x * blockDim.x + threadIdx.x;
  const int eStride = (gridDim.x * blockDim.x) >> 2;
  for (int e = t >> 2; e < nE; e += eStride) {
    unsigned int pos = 0;
    if (q == 0) {
      const int d = ei[nE + e];
      pos = atomicAdd(&cursors[d], 1u);
      sortedSrc[pos] = (unsigned int)ei[e];
    }
    pos = (unsigned int)__shfl((int)pos, lane & ~3);
    const f4_t* ap = (const f4_t*)(ea + (size_t)e * EDIM + q * 8);
    f4_t a0 = __builtin_nontemporal_load(ap);
    f4_t a1 = __builtin_nontemporal_load(ap + 1);
    bf16x8 o;
#pragma unroll
    for (int k = 0; k < 4; ++k) { o[k] = (short)f2bf(a0[k]); o[k + 4] = (short)f2bf(a1[k]); }
    *(bf16x8*)(eaSorted + (size_t)pos * EDIM + q * 8) = o;
  }
}

// Fallback scatter (minimal workspace): eid + src.
__global__ __launch_bounds__(256) void scatter_min(const int* __restrict__ ei,
                                                   unsigned int* __restrict__ cursors,
                                                   unsigned int* __restrict__ sortedEid,
                                                   unsigned int* __restrict__ sortedSrc,
                                                   int nE) {
  int i = blockIdx.x * blockDim.x + threadIdx.x;
  const int stride = gridDim.x * blockDim.x;
  for (; i < nE; i += stride) {
    const int d = ei[nE + i];
    const unsigned int pos = atomicAdd(&cursors[d], 1u);
    sortedEid[pos] = (unsigned int)i;
    sortedSrc[pos] = (unsigned int)ei[i];
  }
}

// ---------------------------------------------------------------------------
// Pair aggregation (r10 exact): one wave per TWO adjacent nodes, both load
// chains in flight together. Register accumulators + shfl reduce; no atomics.
// Natural VGPR (112) -> 4 waves/SIMD. 3-chain variants regressed twice
// (r7: shfl GETSRC; r11: sched_barrier pin) -- this is the local optimum.
// ---------------------------------------------------------------------------
template <int BF16H>
__global__ __launch_bounds__(256) void agg_pair(
    const float* __restrict__ x, const unsigned short* __restrict__ xPerm,
    const unsigned short* __restrict__ eaSorted, const unsigned int* __restrict__ sortedSrc,
    const float* __restrict__ W, const float* __restrict__ bias,
    const unsigned int* __restrict__ offsets, float* __restrict__ h,
    unsigned short* __restrict__ hBf, int nNodes, int nPairs) {
  const int lane = threadIdx.x & 63;
  const int l15 = lane & 15;
  const int lq  = lane >> 4;

  bf16x8 Wf[8];
  float bv[8];
#pragma unroll
  for (int nt = 0; nt < 8; ++nt) {
#pragma unroll
    for (int j = 0; j < 8; ++j)
      Wf[nt][j] = (short)f2bf(W[(8 * lq + j) * HID + 16 * nt + l15]);
    bv[nt] = bias[16 * nt + l15];
  }

  int waveId = blockIdx.x * 4 + ((int)threadIdx.x >> 6);
  const int nWaves = gridDim.x * 4;

  auto LOADT = [&](unsigned int b, unsigned int end, bf16x8& af, bf16x8* xg) {
    const unsigned int sA = b + (unsigned int)l15;
    if (sA < end)
      af = __builtin_nontemporal_load((const bf16x8*)(eaSorted + (size_t)sA * EDIM + lq * 8));
    else
      af = bf16x8{0, 0, 0, 0, 0, 0, 0, 0};
#pragma unroll
    for (int r = 0; r < 4; ++r) {
      unsigned int sl = b + (unsigned int)(lq * 4 + r);
      unsigned int cl = sl < end ? sl : end - 1;
      const unsigned int src = sortedSrc[cl];
      xg[r] = *(const bf16x8*)(xPerm + (size_t)src * HID + l15 * 8);
    }
  };

  for (int p = waveId; p < nPairs; p += nWaves) {
    const int nA = p * 2;
    const int nB = (nA + 1 < nNodes) ? nA + 1 : nA;
    unsigned int bA = offsets[nA];
    const unsigned int eA = offsets[nA + 1];
    unsigned int bB = offsets[nB];
    const unsigned int eB = offsets[nB + 1];

    float accA[8] = {0, 0, 0, 0, 0, 0, 0, 0};
    float accB[8] = {0, 0, 0, 0, 0, 0, 0, 0};

    while (bA < eA || bB < eB) {
      const bool mA = bA < eA, mB = bB < eB;
      bf16x8 afA, afB, xgA[4], xgB[4];
      if (mA) LOADT(bA, eA, afA, xgA);
      if (mB) LOADT(bB, eB, afB, xgB);

      if (mA) {
        f4_t acc[8];
#pragma unroll
        for (int nt = 0; nt < 8; ++nt) {
          f4_t c; c[0] = bv[nt]; c[1] = bv[nt]; c[2] = bv[nt]; c[3] = bv[nt];
          acc[nt] = __builtin_amdgcn_mfma_f32_16x16x32_bf16(afA, Wf[nt], c, 0, 0, 0);
        }
#pragma unroll
        for (int r = 0; r < 4; ++r) {
          if (bA + (unsigned int)(lq * 4 + r) < eA) {
#pragma unroll
            for (int nt = 0; nt < 8; ++nt)
              accA[nt] += fmaxf(acc[nt][r] + bf2f(xgA[r][nt]), 0.f);
          }
        }
        bA += 16;
      }

      if (mB) {
        f4_t acc[8];
#pragma unroll
        for (int nt = 0; nt < 8; ++nt) {
          f4_t c; c[0] = bv[nt]; c[1] = bv[nt]; c[2] = bv[nt]; c[3] = bv[nt];
          acc[nt] = __builtin_amdgcn_mfma_f32_16x16x32_bf16(afB, Wf[nt], c, 0, 0, 0);
        }
#pragma unroll
        for (int r = 0; r < 4; ++r) {
          if (bB + (unsigned int)(lq * 4 + r) < eB) {
#pragma unroll
            for (int nt = 0; nt < 8; ++nt)
              accB[nt] += fmaxf(acc[nt][r] + bf2f(xgB[r][nt]), 0.f);
          }
        }
        bB += 16;
      }
    }

#pragma unroll
    for (int nt = 0; nt < 8; ++nt) {
      accA[nt] += __shfl_xor(accA[nt], 16);
      accA[nt] += __shfl_xor(accA[nt], 32);
      accB[nt] += __shfl_xor(accB[nt], 16);
      accB[nt] += __shfl_xor(accB[nt], 32);
    }

    const int c0 = 32 * lq + l15;
    const size_t rowA = (size_t)nA * HID;
    const size_t rowB = (size_t)nB * HID;
    if (BF16H) {
      const unsigned int xvA = *(const unsigned int*)(xPerm + rowA + l15 * 8 + 2 * lq);
      const unsigned int xvB = *(const unsigned int*)(xPerm + rowB + l15 * 8 + 2 * lq);
      hBf[rowA + c0]      = f2bf(accA[2 * lq]     + bf2f((short)(xvA & 0xffffu)));
      hBf[rowA + c0 + 16] = f2bf(accA[2 * lq + 1] + bf2f((short)(xvA >> 16)));
      hBf[rowB + c0]      = f2bf(accB[2 * lq]     + bf2f((short)(xvB & 0xffffu)));
      hBf[rowB + c0 + 16] = f2bf(accB[2 * lq + 1] + bf2f((short)(xvB >> 16)));
    } else {
      h[rowA + c0]      = accA[2 * lq]     + x[rowA + c0];
      h[rowA + c0 + 16] = accA[2 * lq + 1] + x[rowA + c0 + 16];
      h[rowB + c0]      = accB[2 * lq]     + x[rowB + c0];
      h[rowB + c0 + 16] = accB[2 * lq + 1] + x[rowB + c0 + 16];
    }
  }
}

// ---------------------------------------------------------------------------
// Fallback aggregation (minimal workspace): per-node waves, f32 gathers.
// ---------------------------------------------------------------------------
__global__ __launch_bounds__(256) void agg_fb(
    const float* __restrict__ x, const float* __restrict__ ea,
    const float* __restrict__ W, const float* __restrict__ bias,
    const unsigned int* __restrict__ offsets, const unsigned int* __restrict__ sortedEid,
    const unsigned int* __restrict__ sortedSrc, float* __restrict__ h, int nNodes) {
  const int lane = threadIdx.x & 63;
  const int l15 = lane & 15;
  const int lq  = lane >> 4;

  bf16x8 Wf[8];
  float bv[8];
#pragma unroll
  for (int nt = 0; nt < 8; ++nt) {
#pragma unroll
    for (int j = 0; j < 8; ++j)
      Wf[nt][j] = (short)f2bf(W[(8 * lq + j) * HID + 16 * nt + l15]);
    bv[nt] = bias[16 * nt + l15];
  }

  int waveId = blockIdx.x * 4 + ((int)threadIdx.x >> 6);
  const int nWaves = gridDim.x * 4;

  for (int n = waveId; n < nNodes; n += nWaves) {
    const unsigned int beg = offsets[n];
    const unsigned int end = offsets[n + 1];
    float accv[8] = {0, 0, 0, 0, 0, 0, 0, 0};

    for (unsigned int base = beg; base < end; base += 16) {
      bf16x8 af = {0, 0, 0, 0, 0, 0, 0, 0};
      const unsigned int slotA = base + (unsigned int)l15;
      if (slotA < end) {
        const unsigned int eidA = sortedEid[slotA];
        const float* ap = ea + (size_t)eidA * EDIM + 8 * lq;
        f4_t a0 = *(const f4_t*)ap;
        f4_t a1 = *(const f4_t*)(ap + 4);
#pragma unroll
        for (int j = 0; j < 4; ++j) { af[j] = (short)f2bf(a0[j]); af[j + 4] = (short)f2bf(a1[j]); }
      }
      f4_t acc[8];
#pragma unroll
      for (int nt = 0; nt < 8; ++nt) {
        f4_t c; c[0] = bv[nt]; c[1] = bv[nt]; c[2] = bv[nt]; c[3] = bv[nt];
        acc[nt] = __builtin_amdgcn_mfma_f32_16x16x32_bf16(af, Wf[nt], c, 0, 0, 0);
      }
#pragma unroll
      for (int r = 0; r < 4; ++r) {
        const unsigned int slot = base + (unsigned int)(lq * 4 + r);
        if (slot < end) {
          const int s = (int)sortedSrc[slot];
          const float* xp = x + (size_t)s * HID + l15;
#pragma unroll
          for (int nt = 0; nt < 8; ++nt)
            accv[nt] += fmaxf(acc[nt][r] + xp[nt * 16], 0.f);
        }
      }
    }

#pragma unroll
    for (int nt = 0; nt < 8; ++nt) {
      accv[nt] += __shfl_xor(accv[nt], 16);
      accv[nt] += __shfl_xor(accv[nt], 32);
    }
    const int c0 = 32 * lq + l15;
    const size_t rowOff = (size_t)n * HID;
    h[rowOff + c0]      = accv[2 * lq]     + x[rowOff + c0];
    h[rowOff + c0 + 16] = accv[2 * lq + 1] + x[rowOff + c0 + 16];
  }
}

// ---------------------------------------------------------------------------
// Fused node pass: h1 = relu(h@W1+b1) ; h2 = h1@W2+b2 (+ stats).
// BF16H=1: bf16 h in/out (hBf).  BF16H=0: f32 h in/out (hF).
// NWAVES: waves per block. Mode-2 launch uses 1024 threads (NWAVES=16):
// LDS = 32+32+64 = 128 KB -> 1 block/CU but 16 waves/CU = 4 waves/SIMD,
// 2x the residency of the 256-thread/80KB version (r10's latency limiter).
// ---------------------------------------------------------------------------
template <int BF16H, int NWAVES>
__global__ __launch_bounds__(NWAVES * 64) void node_kernel(
    float* __restrict__ hF, unsigned short* __restrict__ hBf,
    const float* __restrict__ W1, const float* __restrict__ b1,
    const float* __restrict__ W2, const float* __restrict__ b2,
    float* __restrict__ stats, int nNodes, int nTiles) {
  __shared__ unsigned short sW1[128 * 128];
  __shared__ unsigned short sW2[128 * 128];
  __shared__ unsigned short sH1[NWAVES][16 * 128];

  const int nThr = NWAVES * 64;
  for (int idx = threadIdx.x; idx < 128 * 128; idx += nThr) {
    int n = idx & 127, k = idx >> 7;
    int off = n * 128 + ((((k >> 3) ^ (n & 15))) << 3) + (k & 7);
    sW1[off] = f2bf(W1[k * HID + n]);
    sW2[off] = f2bf(W2[k * HID + n]);
  }
  __syncthreads();

  const int lane = threadIdx.x & 63;
  const int l15 = lane & 15, lq = lane >> 4;
  const int wv = threadIdx.x >> 6;
  unsigned short* hb = &sH1[wv][0];

  float b1v[8], b2v[8];
#pragma unroll
  for (int nt = 0; nt < 8; ++nt) { b1v[nt] = b1[nt * 16 + l15]; b2v[nt] = b2[nt * 16 + l15]; }
  float ssum[8] = {0, 0, 0, 0, 0, 0, 0, 0};
  float ssq[8]  = {0, 0, 0, 0, 0, 0, 0, 0};

  int waveId = blockIdx.x * NWAVES + wv;
  const int nWaves = gridDim.x * NWAVES;

  for (int tile = waveId; tile < nTiles; tile += nWaves) {
    const int r0 = tile << 4;
    int rr = r0 + l15; if (rr >= nNodes) rr = nNodes - 1;

    bf16x8 af[4];
    if (BF16H) {
      const unsigned short* hp = hBf + (size_t)rr * HID;
#pragma unroll
      for (int kt = 0; kt < 4; ++kt)
        af[kt] = *(const bf16x8*)(hp + kt * 32 + 8 * lq);
    } else {
      const float* hp = hF + (size_t)rr * HID;
#pragma unroll
      for (int kt = 0; kt < 4; ++kt) {
        const int k0 = kt * 32 + 8 * lq;
        f4_t u0 = *(const f4_t*)(hp + k0);
        f4_t u1 = *(const f4_t*)(hp + k0 + 4);
#pragma unroll
        for (int j = 0; j < 4; ++j) {
          af[kt][j]     = (short)f2bf(u0[j]);
          af[kt][j + 4] = (short)f2bf(u1[j]);
        }
      }
    }

    f4_t acc[8];
#pragma unroll
    for (int nt = 0; nt < 8; ++nt) {
      f4_t c; c[0] = b1v[nt]; c[1] = b1v[nt]; c[2] = b1v[nt]; c[3] = b1v[nt];
#pragma unroll
      for (int kt = 0; kt < 4; ++kt) {
        bf16x8 wf = *(const bf16x8*)&sW1[(nt * 16 + l15) * 128 + ((((kt * 4 + lq) ^ l15)) << 3)];
        c = __builtin_amdgcn_mfma_f32_16x16x32_bf16(af[kt], wf, c, 0, 0, 0);
      }
      acc[nt] = c;
    }

#pragma unroll
    for (int nt = 0; nt < 8; ++nt) {
      const int ghi = 2 * nt + (l15 >> 3);
#pragma unroll
      for (int r = 0; r < 4; ++r) {
        const int row = lq * 4 + r;
        hb[row * 128 + ((ghi ^ (row & 15)) << 3) + (l15 & 7)] = f2bf(fmaxf(acc[nt][r], 0.f));
      }
    }
    asm volatile("s_waitcnt lgkmcnt(0)" ::: "memory");
    __builtin_amdgcn_sched_barrier(0);

    bf16x8 af2[4];
#pragma unroll
    for (int kt = 0; kt < 4; ++kt)
      af2[kt] = *(const bf16x8*)&hb[l15 * 128 + ((((kt * 4 + lq) ^ l15)) << 3)];

    f4_t acc2[8];
#pragma unroll
    for (int nt = 0; nt < 8; ++nt) {
      f4_t c; c[0] = b2v[nt]; c[1] = b2v[nt]; c[2] = b2v[nt]; c[3] = b2v[nt];
#pragma unroll
      for (int kt = 0; kt < 4; ++kt) {
        bf16x8 wf = *(const bf16x8*)&sW2[(nt * 16 + l15) * 128 + ((((kt * 4 + lq) ^ l15)) << 3)];
        c = __builtin_amdgcn_mfma_f32_16x16x32_bf16(af2[kt], wf, c, 0, 0, 0);
      }
      acc2[nt] = c;
    }

#pragma unroll
    for (int nt = 0; nt < 8; ++nt) {
#pragma unroll
      for (int r = 0; r < 4; ++r) {
        const int row = r0 + lq * 4 + r;
        if (row < nNodes) {
          float v = acc2[nt][r];
          if (BF16H) hBf[(size_t)row * HID + nt * 16 + l15] = f2bf(v);
          else       hF[(size_t)row * HID + nt * 16 + l15] = v;
          ssum[nt] += v; ssq[nt] += v * v;
        }
      }
    }
  }

#pragma unroll
  for (int nt = 0; nt < 8; ++nt) {
    float a = ssum[nt], b = ssq[nt];
    a += __shfl_xor(a, 16); b += __shfl_xor(b, 16);
    a += __shfl_xor(a, 32); b += __shfl_xor(b, 32);
    if (lq == 0) {
      atomAddF(&stats[nt * 16 + l15], a);
      atomAddF(&stats[HID + nt * 16 + l15], b);
    }
  }
}

__global__ void norm_prep(float* __restrict__ stats, const float* __restrict__ gw,
                          const float* __restrict__ gb, const float* __restrict__ gs,
                          int nNodes) {
  int c = threadIdx.x;
  if (c < HID) {
    float invN = 1.f / (float)nNodes;
    float m   = stats[c] * invN;
    float msq = stats[HID + c] * invN;
    float s   = gs[c];
    float var = msq - (2.f * s - s * s) * m * m;
    float A = gw[c] * rsqrtf(var + 1e-5f);
    float B = gb[c] - A * s * m;
    stats[2 * HID + c] = A;
    stats[3 * HID + c] = B;
  }
}

// norm from bf16 h2 -> f32 out
__global__ __launch_bounds__(256) void norm_bf(const float* __restrict__ stats,
                                               const unsigned short* __restrict__ hBf,
                                               float* __restrict__ out, int total8) {
  const float* A = stats + 2 * HID;
  const float* B = stats + 3 * HID;
  int i = blockIdx.x * blockDim.x + threadIdx.x;
  const int stride = gridDim.x * blockDim.x;
  for (; i < total8; i += stride) {
    const int cg = (i & 15) * 8;
    bf16x8 hv = *(const bf16x8*)(hBf + (size_t)i * 8);
    f4_t a0 = *(const f4_t*)(A + cg), a1 = *(const f4_t*)(A + cg + 4);
    f4_t b0 = *(const f4_t*)(B + cg), b1 = *(const f4_t*)(B + cg + 4);
    f4_t o0, o1;
#pragma unroll
    for (int j = 0; j < 4; ++j) {
      o0[j] = fmaxf(fmaf(bf2f(hv[j]), a0[j], b0[j]), 0.f);
      o1[j] = fmaxf(fmaf(bf2f(hv[j + 4]), a1[j], b1[j]), 0.f);
    }
    f4_t* op = (f4_t*)(out + (size_t)i * 8);
    op[0] = o0; op[1] = o1;
  }
}

// in-place f32 norm (fallback)
__global__ __launch_bounds__(256) void norm_kernel(const float* __restrict__ stats,
                                                   float* __restrict__ out, int total4) {
  const f4_t* A4 = (const f4_t*)(stats + 2 * HID);
  const f4_t* B4 = (const f4_t*)(stats + 3 * HID);
  int i = blockIdx.x * blockDim.x + threadIdx.x;
  const int stride = gridDim.x * blockDim.x;
  for (; i < total4; i += stride) {
    const int cg = i & 31;
    f4_t h = ((const f4_t*)out)[i];
    f4_t a = A4[cg], b = B4[cg];
    f4_t o;
#pragma unroll
    for (int j = 0; j < 4; ++j) o[j] = fmaxf(fmaf(h[j], a[j], b[j]), 0.f);
    ((f4_t*)out)[i] = o;
  }
}

extern "C" void kernel_launch(void* const* d_in, const int* in_sizes, int n_in,
                              void* d_out, int out_size, void* d_ws, size_t ws_size,
                              hipStream_t stream) {
  const float* x  = (const float*)d_in[0];
  const int*   ei = (const int*)d_in[1];
  const float* ea = (const float*)d_in[2];
  const float* eW = (const float*)d_in[3];
  const float* eb = (const float*)d_in[4];
  const float* W1 = (const float*)d_in[5];
  const float* b1 = (const float*)d_in[6];
  const float* W2 = (const float*)d_in[7];
  const float* b2 = (const float*)d_in[8];
  const float* gw = (const float*)d_in[9];
  const float* gb = (const float*)d_in[10];
  const float* gs = (const float*)d_in[11];
  float* out = (float*)d_out;

  const int nNodes = in_sizes[0] / HID;   // 100000
  const int nE     = in_sizes[1] / 2;     // 1600000

  // ws layout
  char* w = (char*)d_ws;
  const size_t offStats   = 0;                                   // 4*HID f32
  const size_t offCounts  = 2048;
  const size_t offCursors = offCounts  + (size_t)nNodes * 4;
  const size_t offOffsets = offCursors + (size_t)nNodes * 4;
  const size_t offChunk   = offOffsets + (((size_t)(nNodes + 1) * 4 + 63) & ~63ull);
  const size_t offSS      = (offChunk + 2048 + 63) & ~63ull;     // nE u32
  const size_t offEaS     = offSS + (size_t)nE * 4;              // nE*EDIM bf16
  const size_t offXP      = offEaS + (size_t)nE * EDIM * 2;      // nNodes*HID bf16
  const size_t needFlat   = offXP + (size_t)nNodes * HID * 2;
  const size_t offHBf     = needFlat;                            // nNodes*HID bf16
  const size_t needBf     = offHBf + (size_t)nNodes * HID * 2;

  float* stats            = (float*)(w + offStats);
  unsigned int* counts    = (unsigned int*)(w + offCounts);
  unsigned int* cursors   = (unsigned int*)(w + offCursors);
  unsigned int* offsets   = (unsigned int*)(w + offOffsets);
  unsigned int* chunkSum  = (unsigned int*)(w + offChunk);
  unsigned int* chunkOff  = (unsigned int*)(w + offChunk + 1024);
  unsigned int* sortedSrc = (unsigned int*)(w + offSS);
  unsigned int* sortedEid = (unsigned int*)(w + offEaS);         // fb reuse
  unsigned short* eaSorted= (unsigned short*)(w + offEaS);
  unsigned short* xPerm   = (unsigned short*)(w + offXP);
  unsigned short* hBf     = (unsigned short*)(w + offHBf);

  const int mode = (ws_size >= needBf) ? 2 : (ws_size >= needFlat ? 1 : 0);

  hipMemsetAsync(d_ws, 0, offCursors, stream);  // stats + counts

  hist_xperm<<<2048, 256, 0, stream>>>(ei, x, counts, xPerm, nE, nNodes, mode >= 1);

  const int nChunks = (nNodes + 1023) / 1024;
  chunk_sum<<<nChunks, 1024, 0, stream>>>(counts, chunkSum, nNodes);
  scan_chunks<<<1, 256, 0, stream>>>(chunkSum, chunkOff, offsets, nChunks, nNodes);
  scan_local<<<nChunks, 1024, 0, stream>>>(counts, chunkOff, offsets, cursors, nNodes);

  const int nTiles = (nNodes + 15) >> 4;

  if (mode >= 1) {
    scatter_conv<<<4096, 256, 0, stream>>>(ei, ea, cursors, sortedSrc, eaSorted, nE);
    const int nPairs = (nNodes + 1) / 2;
    const int blocks = (nPairs + 7) / 8;   // 2 pairs per wave
    if (mode == 2) {
      agg_pair<1><<<blocks, 256, 0, stream>>>(x, xPerm, eaSorted, sortedSrc, eW, eb,
                                              offsets, out, hBf, nNodes, nPairs);
      node_kernel<1, 16><<<256, 1024, 0, stream>>>(nullptr, hBf, W1, b1, W2, b2, stats,
                                                   nNodes, nTiles);
      norm_prep<<<1, 128, 0, stream>>>(stats, gw, gb, gs, nNodes);
      norm_bf<<<2048, 256, 0, stream>>>(stats, hBf, out, nNodes * (HID / 8));
    } else {
      agg_pair<0><<<blocks, 256, 0, stream>>>(x, xPerm, eaSorted, sortedSrc, eW, eb,
                                              offsets, out, hBf, nNodes, nPairs);
      node_kernel<0, 4><<<512, 256, 0, stream>>>(out, nullptr, W1, b1, W2, b2, stats,
                                                 nNodes, nTiles);
      norm_prep<<<1, 128, 0, stream>>>(stats, gw, gb, gs, nNodes);
      norm_kernel<<<2048, 256, 0, stream>>>(stats, out, nNodes * (HID / 4));
    }
  } else {
    scatter_min<<<1024, 256, 0, stream>>>(ei, cursors, sortedEid, sortedSrc, nE);
    agg_fb<<<8192, 256, 0, stream>>>(x, ea, eW, eb, offsets, sortedEid, sortedSrc, out, nNodes);
    node_kernel<0, 4><<<512, 256, 0, stream>>>(out, nullptr, W1, b1, W2, b2, stats,
                                               nNodes, nTiles);
    norm_prep<<<1, 128, 0, stream>>>(stats, gw, gb, gs, nNodes);
    norm_kernel<<<2048, 256, 0, stream>>>(stats, out, nNodes * (HID / 4));
  }
}

// Round 14
// 419.148 us; speedup vs baseline: 1.1647x; 1.1536x over previous
//
#include <hip/hip_runtime.h>
#include <stdint.h>

#define HID 128
#define EDIM 32

typedef __attribute__((ext_vector_type(8))) short bf16x8;
typedef __attribute__((ext_vector_type(4))) float f4_t;

static __device__ __forceinline__ unsigned short f2bf(float f) {
  union { float f; unsigned int u; } v; v.f = f;
  return (unsigned short)((v.u + 0x7fffu + ((v.u >> 16) & 1u)) >> 16);
}

static __device__ __forceinline__ float bf2f(short s) {
  union { unsigned int u; float f; } v;
  v.u = ((unsigned int)(unsigned short)s) << 16;
  return v.f;
}

static __device__ __forceinline__ void atomAddF(float* p, float v) {
#if defined(__gfx950__) || defined(__gfx942__) || defined(__gfx90a__)
  unsafeAtomicAdd(p, v);
#else
  atomicAdd(p, v);
#endif
}

// ---------------------------------------------------------------------------
// Pass 1: histogram of dst + x_perm build:
//   x_perm[node][(c&15)*8 + (c>>4)] = bf16(x[node][c])
// ---------------------------------------------------------------------------
__global__ __launch_bounds__(256) void hist_xperm(const int* __restrict__ ei,
                                                  const float* __restrict__ x,
                                                  unsigned int* __restrict__ counts,
                                                  unsigned short* __restrict__ xPerm,
                                                  int nE, int nNodes, int doPerm) {
  int tid = blockIdx.x * blockDim.x + threadIdx.x;
  const int stride = gridDim.x * blockDim.x;
  for (int i = tid; i < nE; i += stride) atomicAdd(&counts[ei[nE + i]], 1u);
  if (doPerm) {
    const int nCh = nNodes * 16;
    for (int j = tid; j < nCh; j += stride) {
      const int node = j >> 4, g = j & 15;
      const float* xp = x + (size_t)node * HID + g;
      bf16x8 o;
#pragma unroll
      for (int k = 0; k < 8; ++k) o[k] = (short)f2bf(xp[k * 16]);
      *(bf16x8*)(xPerm + (size_t)node * HID + g * 8) = o;
    }
  }
}

// ---------------------------------------------------------------------------
// Chunked exclusive scan of counts[N] -> offsets[N+1]; also fills cursors.
// ---------------------------------------------------------------------------
__global__ __launch_bounds__(1024) void chunk_sum(const unsigned int* __restrict__ counts,
                                                  unsigned int* __restrict__ chunkSum, int N) {
  __shared__ unsigned int wsum[16];
  const int tid = threadIdx.x;
  const int i = blockIdx.x * 1024 + tid;
  unsigned int v = (i < N) ? counts[i] : 0u;
#pragma unroll
  for (int d = 1; d < 64; d <<= 1) v += (unsigned int)__shfl_xor((int)v, d);
  if ((tid & 63) == 0) wsum[tid >> 6] = v;
  __syncthreads();
  if (tid < 16) {
    unsigned int t = wsum[tid];
#pragma unroll
    for (int d = 1; d < 16; d <<= 1) t += (unsigned int)__shfl_xor((int)t, d);
    if (tid == 0) chunkSum[blockIdx.x] = t;
  }
}

__global__ __launch_bounds__(256) void scan_chunks(const unsigned int* __restrict__ chunkSum,
                                                   unsigned int* __restrict__ chunkOff,
                                                   unsigned int* __restrict__ offsets,
                                                   int nChunks, int N) {
  __shared__ unsigned int wsum[4];
  const int tid = threadIdx.x, lane = tid & 63, w = tid >> 6;
  unsigned int v = (tid < nChunks) ? chunkSum[tid] : 0u;
  unsigned int s = v;
#pragma unroll
  for (int d = 1; d < 64; d <<= 1) {
    unsigned int t = (unsigned int)__shfl_up((int)s, d);
    if (lane >= d) s += t;
  }
  if (lane == 63) wsum[w] = s;
  __syncthreads();
  unsigned int wOff = 0;
  for (int k = 0; k < w; ++k) wOff += wsum[k];
  if (tid < nChunks) chunkOff[tid] = wOff + s - v;
  if (tid == nChunks - 1) offsets[N] = wOff + s;
}

__global__ __launch_bounds__(1024) void scan_local(const unsigned int* __restrict__ counts,
                                                   const unsigned int* __restrict__ chunkOff,
                                                   unsigned int* __restrict__ offsets,
                                                   unsigned int* __restrict__ cursors, int N) {
  __shared__ unsigned int wsum[16];
  const int tid = threadIdx.x, lane = tid & 63, w = tid >> 6;
  const int i = blockIdx.x * 1024 + tid;
  unsigned int v = (i < N) ? counts[i] : 0u;
  unsigned int s = v;
#pragma unroll
  for (int d = 1; d < 64; d <<= 1) {
    unsigned int t = (unsigned int)__shfl_up((int)s, d);
    if (lane >= d) s += t;
  }
  if (lane == 63) wsum[w] = s;
  __syncthreads();
  unsigned int wOff = 0;
  for (int k = 0; k < w; ++k) wOff += wsum[k];
  if (i < N) {
    const unsigned int ex = chunkOff[blockIdx.x] + wOff + (s - v);
    offsets[i] = ex;
    cursors[i] = ex;
  }
}

// ---------------------------------------------------------------------------
// Fused scatter + ea convert: 4 lanes per edge. Writes sortedSrc[pos] (4 B)
// and eaSorted[pos] (64 B bf16 row, NORMAL stores so L3 keeps them for agg).
// ---------------------------------------------------------------------------
__global__ __launch_bounds__(256) void scatter_conv(const int* __restrict__ ei,
                                                    const float* __restrict__ ea,
                                                    unsigned int* __restrict__ cursors,
                                                    unsigned int* __restrict__ sortedSrc,
                                                    unsigned short* __restrict__ eaSorted,
                                                    int nE) {
  const int lane = threadIdx.x & 63;
  const int q = lane & 3;
  int t = blockIdx.x * blockDim.x + threadIdx.x;
  const int eStride = (gridDim.x * blockDim.x) >> 2;
  for (int e = t >> 2; e < nE; e += eStride) {
    unsigned int pos = 0;
    if (q == 0) {
      const int d = ei[nE + e];
      pos = atomicAdd(&cursors[d], 1u);
      sortedSrc[pos] = (unsigned int)ei[e];
    }
    pos = (unsigned int)__shfl((int)pos, lane & ~3);
    const f4_t* ap = (const f4_t*)(ea + (size_t)e * EDIM + q * 8);
    f4_t a0 = __builtin_nontemporal_load(ap);
    f4_t a1 = __builtin_nontemporal_load(ap + 1);
    bf16x8 o;
#pragma unroll
    for (int k = 0; k < 4; ++k) { o[k] = (short)f2bf(a0[k]); o[k + 4] = (short)f2bf(a1[k]); }
    *(bf16x8*)(eaSorted + (size_t)pos * EDIM + q * 8) = o;
  }
}

// Fallback scatter (minimal workspace): eid + src.
__global__ __launch_bounds__(256) void scatter_min(const int* __restrict__ ei,
                                                   unsigned int* __restrict__ cursors,
                                                   unsigned int* __restrict__ sortedEid,
                                                   unsigned int* __restrict__ sortedSrc,
                                                   int nE) {
  int i = blockIdx.x * blockDim.x + threadIdx.x;
  const int stride = gridDim.x * blockDim.x;
  for (; i < nE; i += stride) {
    const int d = ei[nE + i];
    const unsigned int pos = atomicAdd(&cursors[d], 1u);
    sortedEid[pos] = (unsigned int)i;
    sortedSrc[pos] = (unsigned int)ei[i];
  }
}

// ---------------------------------------------------------------------------
// Pair aggregation (best config): one wave per TWO adjacent nodes, both load
// chains in flight together. Register accumulators + shfl reduce; no atomics.
// Natural VGPR (112) -> 4 waves/SIMD. Bracketing evidence: 3-chain variants
// regressed twice (r7 shfl GETSRC, r11 sched_barrier pin); forced occupancy
// (256,5) spilled catastrophically (r9). This is the local optimum.
// ---------------------------------------------------------------------------
template <int BF16H>
__global__ __launch_bounds__(256) void agg_pair(
    const float* __restrict__ x, const unsigned short* __restrict__ xPerm,
    const unsigned short* __restrict__ eaSorted, const unsigned int* __restrict__ sortedSrc,
    const float* __restrict__ W, const float* __restrict__ bias,
    const unsigned int* __restrict__ offsets, float* __restrict__ h,
    unsigned short* __restrict__ hBf, int nNodes, int nPairs) {
  const int lane = threadIdx.x & 63;
  const int l15 = lane & 15;
  const int lq  = lane >> 4;

  bf16x8 Wf[8];
  float bv[8];
#pragma unroll
  for (int nt = 0; nt < 8; ++nt) {
#pragma unroll
    for (int j = 0; j < 8; ++j)
      Wf[nt][j] = (short)f2bf(W[(8 * lq + j) * HID + 16 * nt + l15]);
    bv[nt] = bias[16 * nt + l15];
  }

  int waveId = blockIdx.x * 4 + ((int)threadIdx.x >> 6);
  const int nWaves = gridDim.x * 4;

  auto LOADT = [&](unsigned int b, unsigned int end, bf16x8& af, bf16x8* xg) {
    const unsigned int sA = b + (unsigned int)l15;
    if (sA < end)
      af = __builtin_nontemporal_load((const bf16x8*)(eaSorted + (size_t)sA * EDIM + lq * 8));
    else
      af = bf16x8{0, 0, 0, 0, 0, 0, 0, 0};
#pragma unroll
    for (int r = 0; r < 4; ++r) {
      unsigned int sl = b + (unsigned int)(lq * 4 + r);
      unsigned int cl = sl < end ? sl : end - 1;
      const unsigned int src = sortedSrc[cl];
      xg[r] = *(const bf16x8*)(xPerm + (size_t)src * HID + l15 * 8);
    }
  };

  for (int p = waveId; p < nPairs; p += nWaves) {
    const int nA = p * 2;
    const int nB = (nA + 1 < nNodes) ? nA + 1 : nA;
    unsigned int bA = offsets[nA];
    const unsigned int eA = offsets[nA + 1];
    unsigned int bB = offsets[nB];
    const unsigned int eB = offsets[nB + 1];

    float accA[8] = {0, 0, 0, 0, 0, 0, 0, 0};
    float accB[8] = {0, 0, 0, 0, 0, 0, 0, 0};

    while (bA < eA || bB < eB) {
      const bool mA = bA < eA, mB = bB < eB;
      bf16x8 afA, afB, xgA[4], xgB[4];
      if (mA) LOADT(bA, eA, afA, xgA);
      if (mB) LOADT(bB, eB, afB, xgB);

      if (mA) {
        f4_t acc[8];
#pragma unroll
        for (int nt = 0; nt < 8; ++nt) {
          f4_t c; c[0] = bv[nt]; c[1] = bv[nt]; c[2] = bv[nt]; c[3] = bv[nt];
          acc[nt] = __builtin_amdgcn_mfma_f32_16x16x32_bf16(afA, Wf[nt], c, 0, 0, 0);
        }
#pragma unroll
        for (int r = 0; r < 4; ++r) {
          if (bA + (unsigned int)(lq * 4 + r) < eA) {
#pragma unroll
            for (int nt = 0; nt < 8; ++nt)
              accA[nt] += fmaxf(acc[nt][r] + bf2f(xgA[r][nt]), 0.f);
          }
        }
        bA += 16;
      }

      if (mB) {
        f4_t acc[8];
#pragma unroll
        for (int nt = 0; nt < 8; ++nt) {
          f4_t c; c[0] = bv[nt]; c[1] = bv[nt]; c[2] = bv[nt]; c[3] = bv[nt];
          acc[nt] = __builtin_amdgcn_mfma_f32_16x16x32_bf16(afB, Wf[nt], c, 0, 0, 0);
        }
#pragma unroll
        for (int r = 0; r < 4; ++r) {
          if (bB + (unsigned int)(lq * 4 + r) < eB) {
#pragma unroll
            for (int nt = 0; nt < 8; ++nt)
              accB[nt] += fmaxf(acc[nt][r] + bf2f(xgB[r][nt]), 0.f);
          }
        }
        bB += 16;
      }
    }

#pragma unroll
    for (int nt = 0; nt < 8; ++nt) {
      accA[nt] += __shfl_xor(accA[nt], 16);
      accA[nt] += __shfl_xor(accA[nt], 32);
      accB[nt] += __shfl_xor(accB[nt], 16);
      accB[nt] += __shfl_xor(accB[nt], 32);
    }

    const int c0 = 32 * lq + l15;
    const size_t rowA = (size_t)nA * HID;
    const size_t rowB = (size_t)nB * HID;
    if (BF16H) {
      const unsigned int xvA = *(const unsigned int*)(xPerm + rowA + l15 * 8 + 2 * lq);
      const unsigned int xvB = *(const unsigned int*)(xPerm + rowB + l15 * 8 + 2 * lq);
      hBf[rowA + c0]      = f2bf(accA[2 * lq]     + bf2f((short)(xvA & 0xffffu)));
      hBf[rowA + c0 + 16] = f2bf(accA[2 * lq + 1] + bf2f((short)(xvA >> 16)));
      hBf[rowB + c0]      = f2bf(accB[2 * lq]     + bf2f((short)(xvB & 0xffffu)));
      hBf[rowB + c0 + 16] = f2bf(accB[2 * lq + 1] + bf2f((short)(xvB >> 16)));
    } else {
      h[rowA + c0]      = accA[2 * lq]     + x[rowA + c0];
      h[rowA + c0 + 16] = accA[2 * lq + 1] + x[rowA + c0 + 16];
      h[rowB + c0]      = accB[2 * lq]     + x[rowB + c0];
      h[rowB + c0 + 16] = accB[2 * lq + 1] + x[rowB + c0 + 16];
    }
  }
}

// ---------------------------------------------------------------------------
// Fallback aggregation (minimal workspace): per-node waves, f32 gathers.
// ---------------------------------------------------------------------------
__global__ __launch_bounds__(256) void agg_fb(
    const float* __restrict__ x, const float* __restrict__ ea,
    const float* __restrict__ W, const float* __restrict__ bias,
    const unsigned int* __restrict__ offsets, const unsigned int* __restrict__ sortedEid,
    const unsigned int* __restrict__ sortedSrc, float* __restrict__ h, int nNodes) {
  const int lane = threadIdx.x & 63;
  const int l15 = lane & 15;
  const int lq  = lane >> 4;

  bf16x8 Wf[8];
  float bv[8];
#pragma unroll
  for (int nt = 0; nt < 8; ++nt) {
#pragma unroll
    for (int j = 0; j < 8; ++j)
      Wf[nt][j] = (short)f2bf(W[(8 * lq + j) * HID + 16 * nt + l15]);
    bv[nt] = bias[16 * nt + l15];
  }

  int waveId = blockIdx.x * 4 + ((int)threadIdx.x >> 6);
  const int nWaves = gridDim.x * 4;

  for (int n = waveId; n < nNodes; n += nWaves) {
    const unsigned int beg = offsets[n];
    const unsigned int end = offsets[n + 1];
    float accv[8] = {0, 0, 0, 0, 0, 0, 0, 0};

    for (unsigned int base = beg; base < end; base += 16) {
      bf16x8 af = {0, 0, 0, 0, 0, 0, 0, 0};
      const unsigned int slotA = base + (unsigned int)l15;
      if (slotA < end) {
        const unsigned int eidA = sortedEid[slotA];
        const float* ap = ea + (size_t)eidA * EDIM + 8 * lq;
        f4_t a0 = *(const f4_t*)ap;
        f4_t a1 = *(const f4_t*)(ap + 4);
#pragma unroll
        for (int j = 0; j < 4; ++j) { af[j] = (short)f2bf(a0[j]); af[j + 4] = (short)f2bf(a1[j]); }
      }
      f4_t acc[8];
#pragma unroll
      for (int nt = 0; nt < 8; ++nt) {
        f4_t c; c[0] = bv[nt]; c[1] = bv[nt]; c[2] = bv[nt]; c[3] = bv[nt];
        acc[nt] = __builtin_amdgcn_mfma_f32_16x16x32_bf16(af, Wf[nt], c, 0, 0, 0);
      }
#pragma unroll
      for (int r = 0; r < 4; ++r) {
        const unsigned int slot = base + (unsigned int)(lq * 4 + r);
        if (slot < end) {
          const int s = (int)sortedSrc[slot];
          const float* xp = x + (size_t)s * HID + l15;
#pragma unroll
          for (int nt = 0; nt < 8; ++nt)
            accv[nt] += fmaxf(acc[nt][r] + xp[nt * 16], 0.f);
        }
      }
    }

#pragma unroll
    for (int nt = 0; nt < 8; ++nt) {
      accv[nt] += __shfl_xor(accv[nt], 16);
      accv[nt] += __shfl_xor(accv[nt], 32);
    }
    const int c0 = 32 * lq + l15;
    const size_t rowOff = (size_t)n * HID;
    h[rowOff + c0]      = accv[2 * lq]     + x[rowOff + c0];
    h[rowOff + c0 + 16] = accv[2 * lq + 1] + x[rowOff + c0 + 16];
  }
}

// ---------------------------------------------------------------------------
// Fused node pass (best config: 256 threads, 80 KB LDS, 2 blocks/CU).
// h1 = relu(h@W1+b1) ; h2 = h1@W2+b2 (+ stats).
// BF16H=1: bf16 h in/out (hBf). BF16H=0: f32 h in/out (hF).
// Split kernels (r12, +68us) and 1024-thr/128KB (r13, +63us) both regressed.
// ---------------------------------------------------------------------------
template <int BF16H>
__global__ __launch_bounds__(256) void node_kernel(
    float* __restrict__ hF, unsigned short* __restrict__ hBf,
    const float* __restrict__ W1, const float* __restrict__ b1,
    const float* __restrict__ W2, const float* __restrict__ b2,
    float* __restrict__ stats, int nNodes, int nTiles) {
  __shared__ unsigned short sW1[128 * 128];
  __shared__ unsigned short sW2[128 * 128];
  __shared__ unsigned short sH1[4][16 * 128];

  for (int idx = threadIdx.x; idx < 128 * 128; idx += 256) {
    int n = idx & 127, k = idx >> 7;
    int off = n * 128 + ((((k >> 3) ^ (n & 15))) << 3) + (k & 7);
    sW1[off] = f2bf(W1[k * HID + n]);
    sW2[off] = f2bf(W2[k * HID + n]);
  }
  __syncthreads();

  const int lane = threadIdx.x & 63;
  const int l15 = lane & 15, lq = lane >> 4;
  const int wv = threadIdx.x >> 6;
  unsigned short* hb = &sH1[wv][0];

  float b1v[8], b2v[8];
#pragma unroll
  for (int nt = 0; nt < 8; ++nt) { b1v[nt] = b1[nt * 16 + l15]; b2v[nt] = b2[nt * 16 + l15]; }
  float ssum[8] = {0, 0, 0, 0, 0, 0, 0, 0};
  float ssq[8]  = {0, 0, 0, 0, 0, 0, 0, 0};

  int waveId = blockIdx.x * 4 + wv;
  const int nWaves = gridDim.x * 4;

  for (int tile = waveId; tile < nTiles; tile += nWaves) {
    const int r0 = tile << 4;
    int rr = r0 + l15; if (rr >= nNodes) rr = nNodes - 1;

    bf16x8 af[4];
    if (BF16H) {
      const unsigned short* hp = hBf + (size_t)rr * HID;
#pragma unroll
      for (int kt = 0; kt < 4; ++kt)
        af[kt] = *(const bf16x8*)(hp + kt * 32 + 8 * lq);
    } else {
      const float* hp = hF + (size_t)rr * HID;
#pragma unroll
      for (int kt = 0; kt < 4; ++kt) {
        const int k0 = kt * 32 + 8 * lq;
        f4_t u0 = *(const f4_t*)(hp + k0);
        f4_t u1 = *(const f4_t*)(hp + k0 + 4);
#pragma unroll
        for (int j = 0; j < 4; ++j) {
          af[kt][j]     = (short)f2bf(u0[j]);
          af[kt][j + 4] = (short)f2bf(u1[j]);
        }
      }
    }

    f4_t acc[8];
#pragma unroll
    for (int nt = 0; nt < 8; ++nt) {
      f4_t c; c[0] = b1v[nt]; c[1] = b1v[nt]; c[2] = b1v[nt]; c[3] = b1v[nt];
#pragma unroll
      for (int kt = 0; kt < 4; ++kt) {
        bf16x8 wf = *(const bf16x8*)&sW1[(nt * 16 + l15) * 128 + ((((kt * 4 + lq) ^ l15)) << 3)];
        c = __builtin_amdgcn_mfma_f32_16x16x32_bf16(af[kt], wf, c, 0, 0, 0);
      }
      acc[nt] = c;
    }

#pragma unroll
    for (int nt = 0; nt < 8; ++nt) {
      const int ghi = 2 * nt + (l15 >> 3);
#pragma unroll
      for (int r = 0; r < 4; ++r) {
        const int row = lq * 4 + r;
        hb[row * 128 + ((ghi ^ (row & 15)) << 3) + (l15 & 7)] = f2bf(fmaxf(acc[nt][r], 0.f));
      }
    }
    asm volatile("s_waitcnt lgkmcnt(0)" ::: "memory");
    __builtin_amdgcn_sched_barrier(0);

    bf16x8 af2[4];
#pragma unroll
    for (int kt = 0; kt < 4; ++kt)
      af2[kt] = *(const bf16x8*)&hb[l15 * 128 + ((((kt * 4 + lq) ^ l15)) << 3)];

    f4_t acc2[8];
#pragma unroll
    for (int nt = 0; nt < 8; ++nt) {
      f4_t c; c[0] = b2v[nt]; c[1] = b2v[nt]; c[2] = b2v[nt]; c[3] = b2v[nt];
#pragma unroll
      for (int kt = 0; kt < 4; ++kt) {
        bf16x8 wf = *(const bf16x8*)&sW2[(nt * 16 + l15) * 128 + ((((kt * 4 + lq) ^ l15)) << 3)];
        c = __builtin_amdgcn_mfma_f32_16x16x32_bf16(af2[kt], wf, c, 0, 0, 0);
      }
      acc2[nt] = c;
    }

#pragma unroll
    for (int nt = 0; nt < 8; ++nt) {
#pragma unroll
      for (int r = 0; r < 4; ++r) {
        const int row = r0 + lq * 4 + r;
        if (row < nNodes) {
          float v = acc2[nt][r];
          if (BF16H) hBf[(size_t)row * HID + nt * 16 + l15] = f2bf(v);
          else       hF[(size_t)row * HID + nt * 16 + l15] = v;
          ssum[nt] += v; ssq[nt] += v * v;
        }
      }
    }
  }

#pragma unroll
  for (int nt = 0; nt < 8; ++nt) {
    float a = ssum[nt], b = ssq[nt];
    a += __shfl_xor(a, 16); b += __shfl_xor(b, 16);
    a += __shfl_xor(a, 32); b += __shfl_xor(b, 32);
    if (lq == 0) {
      atomAddF(&stats[nt * 16 + l15], a);
      atomAddF(&stats[HID + nt * 16 + l15], b);
    }
  }
}

__global__ void norm_prep(float* __restrict__ stats, const float* __restrict__ gw,
                          const float* __restrict__ gb, const float* __restrict__ gs,
                          int nNodes) {
  int c = threadIdx.x;
  if (c < HID) {
    float invN = 1.f / (float)nNodes;
    float m   = stats[c] * invN;
    float msq = stats[HID + c] * invN;
    float s   = gs[c];
    float var = msq - (2.f * s - s * s) * m * m;
    float A = gw[c] * rsqrtf(var + 1e-5f);
    float B = gb[c] - A * s * m;
    stats[2 * HID + c] = A;
    stats[3 * HID + c] = B;
  }
}

// norm from bf16 h2 -> f32 out
__global__ __launch_bounds__(256) void norm_bf(const float* __restrict__ stats,
                                               const unsigned short* __restrict__ hBf,
                                               float* __restrict__ out, int total8) {
  const float* A = stats + 2 * HID;
  const float* B = stats + 3 * HID;
  int i = blockIdx.x * blockDim.x + threadIdx.x;
  const int stride = gridDim.x * blockDim.x;
  for (; i < total8; i += stride) {
    const int cg = (i & 15) * 8;
    bf16x8 hv = *(const bf16x8*)(hBf + (size_t)i * 8);
    f4_t a0 = *(const f4_t*)(A + cg), a1 = *(const f4_t*)(A + cg + 4);
    f4_t b0 = *(const f4_t*)(B + cg), b1 = *(const f4_t*)(B + cg + 4);
    f4_t o0, o1;
#pragma unroll
    for (int j = 0; j < 4; ++j) {
      o0[j] = fmaxf(fmaf(bf2f(hv[j]), a0[j], b0[j]), 0.f);
      o1[j] = fmaxf(fmaf(bf2f(hv[j + 4]), a1[j], b1[j]), 0.f);
    }
    f4_t* op = (f4_t*)(out + (size_t)i * 8);
    op[0] = o0; op[1] = o1;
  }
}

// in-place f32 norm (fallback)
__global__ __launch_bounds__(256) void norm_kernel(const float* __restrict__ stats,
                                                   float* __restrict__ out, int total4) {
  const f4_t* A4 = (const f4_t*)(stats + 2 * HID);
  const f4_t* B4 = (const f4_t*)(stats + 3 * HID);
  int i = blockIdx.x * blockDim.x + threadIdx.x;
  const int stride = gridDim.x * blockDim.x;
  for (; i < total4; i += stride) {
    const int cg = i & 31;
    f4_t h = ((const f4_t*)out)[i];
    f4_t a = A4[cg], b = B4[cg];
    f4_t o;
#pragma unroll
    for (int j = 0; j < 4; ++j) o[j] = fmaxf(fmaf(h[j], a[j], b[j]), 0.f);
    ((f4_t*)out)[i] = o;
  }
}

extern "C" void kernel_launch(void* const* d_in, const int* in_sizes, int n_in,
                              void* d_out, int out_size, void* d_ws, size_t ws_size,
                              hipStream_t stream) {
  const float* x  = (const float*)d_in[0];
  const int*   ei = (const int*)d_in[1];
  const float* ea = (const float*)d_in[2];
  const float* eW = (const float*)d_in[3];
  const float* eb = (const float*)d_in[4];
  const float* W1 = (const float*)d_in[5];
  const float* b1 = (const float*)d_in[6];
  const float* W2 = (const float*)d_in[7];
  const float* b2 = (const float*)d_in[8];
  const float* gw = (const float*)d_in[9];
  const float* gb = (const float*)d_in[10];
  const float* gs = (const float*)d_in[11];
  float* out = (float*)d_out;

  const int nNodes = in_sizes[0] / HID;   // 100000
  const int nE     = in_sizes[1] / 2;     // 1600000

  // ws layout
  char* w = (char*)d_ws;
  const size_t offStats   = 0;                                   // 4*HID f32
  const size_t offCounts  = 2048;
  const size_t offCursors = offCounts  + (size_t)nNodes * 4;
  const size_t offOffsets = offCursors + (size_t)nNodes * 4;
  const size_t offChunk   = offOffsets + (((size_t)(nNodes + 1) * 4 + 63) & ~63ull);
  const size_t offSS      = (offChunk + 2048 + 63) & ~63ull;     // nE u32
  const size_t offEaS     = offSS + (size_t)nE * 4;              // nE*EDIM bf16
  const size_t offXP      = offEaS + (size_t)nE * EDIM * 2;      // nNodes*HID bf16
  const size_t needFlat   = offXP + (size_t)nNodes * HID * 2;
  const size_t offHBf     = needFlat;                            // nNodes*HID bf16
  const size_t needBf     = offHBf + (size_t)nNodes * HID * 2;

  float* stats            = (float*)(w + offStats);
  unsigned int* counts    = (unsigned int*)(w + offCounts);
  unsigned int* cursors   = (unsigned int*)(w + offCursors);
  unsigned int* offsets   = (unsigned int*)(w + offOffsets);
  unsigned int* chunkSum  = (unsigned int*)(w + offChunk);
  unsigned int* chunkOff  = (unsigned int*)(w + offChunk + 1024);
  unsigned int* sortedSrc = (unsigned int*)(w + offSS);
  unsigned int* sortedEid = (unsigned int*)(w + offEaS);         // fb reuse
  unsigned short* eaSorted= (unsigned short*)(w + offEaS);
  unsigned short* xPerm   = (unsigned short*)(w + offXP);
  unsigned short* hBf     = (unsigned short*)(w + offHBf);

  const int mode = (ws_size >= needBf) ? 2 : (ws_size >= needFlat ? 1 : 0);

  hipMemsetAsync(d_ws, 0, offCursors, stream);  // stats + counts

  hist_xperm<<<2048, 256, 0, stream>>>(ei, x, counts, xPerm, nE, nNodes, mode >= 1);

  const int nChunks = (nNodes + 1023) / 1024;
  chunk_sum<<<nChunks, 1024, 0, stream>>>(counts, chunkSum, nNodes);
  scan_chunks<<<1, 256, 0, stream>>>(chunkSum, chunkOff, offsets, nChunks, nNodes);
  scan_local<<<nChunks, 1024, 0, stream>>>(counts, chunkOff, offsets, cursors, nNodes);

  const int nTiles = (nNodes + 15) >> 4;

  if (mode >= 1) {
    scatter_conv<<<4096, 256, 0, stream>>>(ei, ea, cursors, sortedSrc, eaSorted, nE);
    const int nPairs = (nNodes + 1) / 2;
    const int blocks = (nPairs + 7) / 8;   // 2 pairs per wave
    if (mode == 2) {
      agg_pair<1><<<blocks, 256, 0, stream>>>(x, xPerm, eaSorted, sortedSrc, eW, eb,
                                              offsets, out, hBf, nNodes, nPairs);
      node_kernel<1><<<512, 256, 0, stream>>>(nullptr, hBf, W1, b1, W2, b2, stats,
                                              nNodes, nTiles);
      norm_prep<<<1, 128, 0, stream>>>(stats, gw, gb, gs, nNodes);
      norm_bf<<<2048, 256, 0, stream>>>(stats, hBf, out, nNodes * (HID / 8));
    } else {
      agg_pair<0><<<blocks, 256, 0, stream>>>(x, xPerm, eaSorted, sortedSrc, eW, eb,
                                              offsets, out, hBf, nNodes, nPairs);
      node_kernel<0><<<512, 256, 0, stream>>>(out, nullptr, W1, b1, W2, b2, stats,
                                              nNodes, nTiles);
      norm_prep<<<1, 128, 0, stream>>>(stats, gw, gb, gs, nNodes);
      norm_kernel<<<2048, 256, 0, stream>>>(stats, out, nNodes * (HID / 4));
    }
  } else {
    scatter_min<<<1024, 256, 0, stream>>>(ei, cursors, sortedEid, sortedSrc, nE);
    agg_fb<<<8192, 256, 0, stream>>>(x, ea, eW, eb, offsets, sortedEid, sortedSrc, out, nNodes);
    node_kernel<0><<<512, 256, 0, stream>>>(out, nullptr, W1, b1, W2, b2, stats,
                                            nNodes, nTiles);
    norm_prep<<<1, 128, 0, stream>>>(stats, gw, gb, gs, nNodes);
    norm_kernel<<<2048, 256, 0, stream>>>(stats, out, nNodes * (HID / 4));
  }
}